// Round 1
// baseline (33.467 us; speedup 1.0000x reference)
//
#include <hip/hip_runtime.h>

#define VOCAB 32000
#define DIM 2048
#define N_LORA 9
#define RANK 16
#define NSEG 16
#define TB 32          // tokens per block tile
#define BLOCK 256      // threads; each owns 4 consecutive dims -> 1024 dims/block

__global__ __launch_bounds__(BLOCK) void lora_embed_kernel(
    const int* __restrict__ input_ids,
    const float* __restrict__ weight,
    const float* __restrict__ A_buffer,
    const float* __restrict__ B_buffer,
    const int* __restrict__ seg_indptr,
    const int* __restrict__ weight_indices,
    const float* __restrict__ scalings,
    float* __restrict__ out,
    int T)
{
    __shared__ int ids_s[TB];
    __shared__ int w_s[TB];
    __shared__ float scale_s[TB];
    __shared__ float4 a_s[TB][RANK / 4];

    const int tid = threadIdx.x;
    const int t0 = blockIdx.x * TB;

    // Phase 1: per-token segment lookup -> lora slot w, scale (0 if w==0)
    if (tid < TB) {
        int tg = t0 + tid;
        int tc = tg < T ? tg : T - 1;
        int id = input_ids[tc];
        // seg = (# of seg_indptr[0..NSEG-1] <= t) - 1  (== searchsorted 'right' - 1;
        // seg_indptr[NSEG] == T is never <= t for t < T)
        int seg = -1;
        #pragma unroll
        for (int i = 0; i < NSEG; ++i)
            seg += (seg_indptr[i] <= tc) ? 1 : 0;
        int w = weight_indices[seg];
        ids_s[tid] = id;
        w_s[tid] = w;
        scale_s[tid] = (w != 0) ? scalings[w] : 0.0f;
    }
    __syncthreads();

    // Phase 2: stage pre-scaled a[t, 0:16] into LDS (float4 quads)
    if (tid < TB * 4) {
        const int t = tid >> 2, q = tid & 3;
        const float4* arow = reinterpret_cast<const float4*>(
            A_buffer + ((size_t)w_s[t] * VOCAB + (size_t)ids_s[t]) * RANK);
        float4 av = arow[q];
        const float s = scale_s[t];
        av.x *= s; av.y *= s; av.z *= s; av.w *= s;
        a_s[t][q] = av;
    }
    __syncthreads();

    // Phase 3: each thread owns dims [d, d+4); B rows for those dims live in
    // registers and are reloaded only when the tile crosses a segment with a
    // different lora slot (rare: <=15 crossings across the whole grid).
    const int d = (blockIdx.y * BLOCK + tid) * 4;

    float4 b[16];   // 4 dims x 16 rank values
    int wcur = -1;

    #pragma unroll 4
    for (int t = 0; t < TB; ++t) {
        const int tg = t0 + t;
        if (tg >= T) break;

        const int w = w_s[t];                 // wave-uniform (LDS broadcast)
        if (w != wcur) {                      // uniform branch
            wcur = w;
            const float4* bp = reinterpret_cast<const float4*>(
                B_buffer + ((size_t)w * DIM + (size_t)d) * RANK);
            #pragma unroll
            for (int j = 0; j < 16; ++j) b[j] = bp[j];
        }

        const float4 a0 = a_s[t][0], a1 = a_s[t][1], a2 = a_s[t][2], a3 = a_s[t][3];

        float4 acc;
        acc.x = b[ 0].x*a0.x + b[ 0].y*a0.y + b[ 0].z*a0.z + b[ 0].w*a0.w
              + b[ 1].x*a1.x + b[ 1].y*a1.y + b[ 1].z*a1.z + b[ 1].w*a1.w
              + b[ 2].x*a2.x + b[ 2].y*a2.y + b[ 2].z*a2.z + b[ 2].w*a2.w
              + b[ 3].x*a3.x + b[ 3].y*a3.y + b[ 3].z*a3.z + b[ 3].w*a3.w;
        acc.y = b[ 4].x*a0.x + b[ 4].y*a0.y + b[ 4].z*a0.z + b[ 4].w*a0.w
              + b[ 5].x*a1.x + b[ 5].y*a1.y + b[ 5].z*a1.z + b[ 5].w*a1.w
              + b[ 6].x*a2.x + b[ 6].y*a2.y + b[ 6].z*a2.z + b[ 6].w*a2.w
              + b[ 7].x*a3.x + b[ 7].y*a3.y + b[ 7].z*a3.z + b[ 7].w*a3.w;
        acc.z = b[ 8].x*a0.x + b[ 8].y*a0.y + b[ 8].z*a0.z + b[ 8].w*a0.w
              + b[ 9].x*a1.x + b[ 9].y*a1.y + b[ 9].z*a1.z + b[ 9].w*a1.w
              + b[10].x*a2.x + b[10].y*a2.y + b[10].z*a2.z + b[10].w*a2.w
              + b[11].x*a3.x + b[11].y*a3.y + b[11].z*a3.z + b[11].w*a3.w;
        acc.w = b[12].x*a0.x + b[12].y*a0.y + b[12].z*a0.z + b[12].w*a0.w
              + b[13].x*a1.x + b[13].y*a1.y + b[13].z*a1.z + b[13].w*a1.w
              + b[14].x*a2.x + b[14].y*a2.y + b[14].z*a2.z + b[14].w*a2.w
              + b[15].x*a3.x + b[15].y*a3.y + b[15].z*a3.z + b[15].w*a3.w;

        const float4 wv = *reinterpret_cast<const float4*>(
            weight + (size_t)ids_s[t] * DIM + d);

        float4 o;
        o.x = wv.x + acc.x; o.y = wv.y + acc.y;
        o.z = wv.z + acc.z; o.w = wv.w + acc.w;
        *reinterpret_cast<float4*>(out + (size_t)tg * DIM + d) = o;
    }
}

extern "C" void kernel_launch(void* const* d_in, const int* in_sizes, int n_in,
                              void* d_out, int out_size, void* d_ws, size_t ws_size,
                              hipStream_t stream) {
    const int*   input_ids      = (const int*)d_in[0];
    const float* weight         = (const float*)d_in[1];
    const float* A_buffer       = (const float*)d_in[2];
    const float* B_buffer       = (const float*)d_in[3];
    const int*   seg_indptr     = (const int*)d_in[4];
    const int*   weight_indices = (const int*)d_in[5];
    const float* scalings       = (const float*)d_in[6];
    float* out = (float*)d_out;

    const int T = in_sizes[0];
    dim3 grid((T + TB - 1) / TB, DIM / (BLOCK * 4));
    lora_embed_kernel<<<grid, BLOCK, 0, stream>>>(
        input_ids, weight, A_buffer, B_buffer,
        seg_indptr, weight_indices, scalings, out, T);
}